// Round 5
// baseline (181.891 us; speedup 1.0000x reference)
//
#include <hip/hip_runtime.h>
#include <hip/hip_bf16.h>

// DeepseekMoE fused, top-2 SPARSE routed experts, 2-phase pipelined GEMMs:
//   router (f32, + bf16 cast of X) -> index build (per-expert token buckets,
//   128-aligned segments) -> MERGED gathered+shared gate/up GEMM
//   (+gelu*u*scale) -> routed down GEMM (bf16 rows) -> shared down GEMM with
//   fused combine. Device tensors are FLOAT32; GEMMs bf16, f32 accumulate.
// GEMM K-loop: double-buffered LDS, counted s_waitcnt vmcnt(8) (never 0 in
// steady state), raw s_barrier; lgkmcnt(0) before the tail barrier guards the
// buffer-overwrite hazard. T=4096, H=1024, E=8, I=512, IS=1024.

typedef short  s16x8 __attribute__((ext_vector_type(8)));
typedef __bf16 bf16x8 __attribute__((ext_vector_type(8)));
typedef float  f32x4 __attribute__((ext_vector_type(4)));

__device__ __forceinline__ float b2f(ushort u) {
  union { unsigned int i; float f; } v; v.i = ((unsigned int)u) << 16; return v.f;
}
__device__ __forceinline__ ushort f2b(float f) {
  union { float f; unsigned int i; } v; v.f = f;
  unsigned int r = v.i + 0x7fffu + ((v.i >> 16) & 1u);
  return (ushort)(r >> 16);
}
__device__ __forceinline__ f32x4 mfma_bf16(s16x8 a, s16x8 b, f32x4 c) {
  return __builtin_amdgcn_mfma_f32_16x16x32_bf16(
      __builtin_bit_cast(bf16x8, a), __builtin_bit_cast(bf16x8, b), c, 0, 0, 0);
}
__device__ __forceinline__ void gll16(const ushort* g, const ushort* l) {
  __builtin_amdgcn_global_load_lds(
      (const __attribute__((address_space(1))) unsigned int*)g,
      (__attribute__((address_space(3))) unsigned int*)l, 16, 0, 0);
}

// -------- tiled transpose + cast, 3 tight-grid variants ----------------------
// MODE 0: expert gate/up, grid (16,32,16): z<8 Weg->GT else Weu->UT.
// MODE 1: expert down,    grid (32,16,8):  Wed->DT (dst offset z*512).
// MODE 2: shared,         grid (32,32,3):  z=0 Wsg->D0, z=1 Wsu->D1, z=2 Wsd->D2.
template<int MODE>
__global__ __launch_bounds__(256) void transpose_k(
    const float* __restrict__ S0, const float* __restrict__ S1,
    const float* __restrict__ S2, ushort* __restrict__ D0,
    ushort* __restrict__ D1, ushort* __restrict__ D2)
{
  const int z = blockIdx.z;
  const float* src; ushort* dst; int srcLd, dstLd;
  if (MODE == 0) {
    src = (z < 8 ? S0 + (size_t)z * 512 * 1024 : S1 + (size_t)(z - 8) * 512 * 1024);
    dst = (z < 8 ? D0 + (size_t)z * 512 * 1024 : D1 + (size_t)(z - 8) * 512 * 1024);
    srcLd = 512; dstLd = 1024;
  } else if (MODE == 1) {
    src = S0 + (size_t)z * 512 * 1024; dst = D0 + (size_t)z * 512;
    srcLd = 1024; dstLd = 5120;
  } else {
    src = (z == 0 ? S0 : z == 1 ? S1 : S2);
    dst = (z == 0 ? D0 : z == 1 ? D1 : D2);
    srcLd = 1024; dstLd = (z == 2 ? 5120 : 1024);
  }
  __shared__ float tile[32][33];
  const int c0 = blockIdx.x * 32, r0 = blockIdx.y * 32;
  const int tx = threadIdx.x & 31, ty = threadIdx.x >> 5;
#pragma unroll
  for (int j = 0; j < 4; ++j)
    tile[ty + j * 8][tx] = src[(size_t)(r0 + ty + j * 8) * srcLd + c0 + tx];
  __syncthreads();
#pragma unroll
  for (int j = 0; j < 4; ++j)
    dst[(size_t)(c0 + ty + j * 8) * dstLd + r0 + tx] = f2b(tile[tx][ty + j * 8]);
}

// ---------------- router (f32) + X->bf16 cast --------------------------------
__global__ __launch_bounds__(256) void router_k(
    const float* __restrict__ X, const float* __restrict__ Gw,
    const float* __restrict__ Temb, const int* __restrict__ task_id,
    const float* __restrict__ Wc, float* __restrict__ scales,
    int* __restrict__ topk, ushort* __restrict__ Xb)
{
  const int wid = threadIdx.x >> 6, lane = threadIdx.x & 63;
  const int t = blockIdx.x * 4 + wid;
  const float* xr = X + t * 1024;
  const float* er = Temb + task_id[0] * 1024;

  float x[16], xe[16];
#pragma unroll
  for (int c = 0; c < 4; ++c) {
    float4 v = *(const float4*)&xr[c * 256 + lane * 4];
    float4 e = *(const float4*)&er[c * 256 + lane * 4];
    x[c * 4 + 0] = v.x; x[c * 4 + 1] = v.y; x[c * 4 + 2] = v.z; x[c * 4 + 3] = v.w;
    xe[c * 4 + 0] = v.x + e.x; xe[c * 4 + 1] = v.y + e.y;
    xe[c * 4 + 2] = v.z + e.z; xe[c * 4 + 3] = v.w + e.w;
  }
#pragma unroll
  for (int c = 0; c < 4; ++c) {
    ushort4 o;
    o.x = f2b(x[c * 4 + 0]); o.y = f2b(x[c * 4 + 1]);
    o.z = f2b(x[c * 4 + 2]); o.w = f2b(x[c * 4 + 3]);
    *(ushort4*)&Xb[t * 1024 + c * 256 + lane * 4] = o;
  }
  float logit[8];
#pragma unroll
  for (int e = 0; e < 8; ++e) {
    float p = 0.f;
#pragma unroll
    for (int c = 0; c < 4; ++c) {
      float4 g = *(const float4*)&Gw[e * 1024 + c * 256 + lane * 4];
      p += xe[c * 4] * g.x + xe[c * 4 + 1] * g.y + xe[c * 4 + 2] * g.z + xe[c * 4 + 3] * g.w;
    }
#pragma unroll
    for (int off = 32; off; off >>= 1) p += __shfl_xor(p, off);
    logit[e] = p;
  }
  float m = logit[0];
#pragma unroll
  for (int e = 1; e < 8; ++e) m = fmaxf(m, logit[e]);
  float pr[8], s = 0.f;
#pragma unroll
  for (int e = 0; e < 8; ++e) { pr[e] = expf(logit[e] - m); s += pr[e]; }
  float inv = 1.f / s;
#pragma unroll
  for (int e = 0; e < 8; ++e) pr[e] *= inv;
  int i1 = 0; float m1 = pr[0];
#pragma unroll
  for (int e = 1; e < 8; ++e) if (pr[e] > m1) { m1 = pr[e]; i1 = e; }
  int i2 = -1; float m2 = -1.f;
#pragma unroll
  for (int e = 0; e < 8; ++e) if (e != i1 && pr[e] > m2) { m2 = pr[e]; i2 = e; }
  float dn = 1.f / (m1 + m2 + 1e-20f);
  float w1 = m1 * dn, w2 = m2 * dn;

  float a0 = 0.f, a1 = 0.f;
#pragma unroll
  for (int c = 0; c < 4; ++c)
#pragma unroll
    for (int j = 0; j < 4; ++j) {
      int h = c * 256 + lane * 4 + j;
      a0 += x[c * 4 + j] * Wc[h * 2];
      a1 += x[c * 4 + j] * Wc[h * 2 + 1];
    }
#pragma unroll
  for (int off = 32; off; off >>= 1) {
    a0 += __shfl_xor(a0, off); a1 += __shfl_xor(a1, off);
  }
  float am = fmaxf(a0, a1);
  float ea0 = expf(a0 - am), ea1 = expf(a1 - am);
  float al0 = ea0 / (ea0 + ea1), al1 = ea1 / (ea0 + ea1);

  if (lane == 0) {
    scales[t * 4 + 0] = al0 * w1;
    scales[t * 4 + 1] = al0 * w2;
    scales[t * 4 + 2] = al1;
    topk[t * 2 + 0] = i1;
    topk[t * 2 + 1] = i2;
  }
}

// ---------------- index build: per-expert 128-aligned token buckets ----------
__global__ __launch_bounds__(256) void indexbuild_k(
    const int* __restrict__ topk, const float* __restrict__ scales,
    int* __restrict__ tokmap, int* __restrict__ tokrows,
    float* __restrict__ rowscale, int* __restrict__ meta)
{
  __shared__ int cnt[8], cnt2[8], base[8];
  const int tid = threadIdx.x;
  if (tid < 8) { cnt[tid] = 0; cnt2[tid] = 0; }
  __syncthreads();
  for (int t = tid; t < 4096; t += 256) {
    atomicAdd(&cnt[topk[t * 2]], 1);
    atomicAdd(&cnt[topk[t * 2 + 1]], 1);
  }
  __syncthreads();
  if (tid == 0) {
    int nb = 0;
    for (int e = 0; e < 8; ++e) {
      base[e] = nb * 128;
      int blocks = (cnt[e] + 127) >> 7;
      for (int j = 0; j < blocks; ++j) meta[nb + j] = e;
      nb += blocks;
    }
    meta[127] = nb;
  }
  __syncthreads();
  for (int t = tid; t < 4096; t += 256) {
#pragma unroll
    for (int r = 0; r < 2; ++r) {
      int e = topk[t * 2 + r];
      int slot = atomicAdd(&cnt2[e], 1);
      int row = base[e] + slot;
      tokmap[row] = t;
      rowscale[row] = scales[t * 4 + r];
      tokrows[t * 2 + r] = row;
    }
  }
  __syncthreads();
  for (int e = 0; e < 8; ++e) {
    int c = cnt[e], R = ((c + 127) >> 7) << 7;
    for (int j = c + tid; j < R; j += 256) {
      tokmap[base[e] + j] = 0;
      rowscale[base[e] + j] = 0.f;
    }
  }
}

// ------- MERGED GEMM1 (2-phase pipelined): routed + shared gate/up -----------
// grid (16, 104). y<72: routed 128-row expert block (x<8 active),
//                 y>=72: shared token block (all 16 x).
// 128 rows x 64 cols, BK=64 dbuf, 4 waves (2x2), wave 64x32, dual G/U acc.
__global__ __launch_bounds__(256) void gemm1_k(
    const ushort* __restrict__ Xb, const ushort* __restrict__ GT,
    const ushort* __restrict__ UT, const float* __restrict__ scales,
    const int* __restrict__ tokmap, const float* __restrict__ rowscale,
    const int* __restrict__ meta, ushort* __restrict__ Bg,
    ushort* __restrict__ Bs)
{
  __shared__ __align__(16) ushort lA[2][128 * 64];
  __shared__ __align__(16) ushort lG[2][64 * 64];
  __shared__ __align__(16) ushort lU[2][64 * 64];
  const int x = blockIdx.x, y = blockIdx.y;
  const bool routed = y < 72;
  if (routed && (x >= 8 || y >= meta[127])) return;

  const int tid = threadIdx.x, wid = tid >> 6, lane = tid & 63;
  const int col0 = x * 64;
  const int row0 = routed ? y * 128 : (y - 72) * 128;
  const int colG = routed ? (meta[y] * 512 + col0) : (4096 + col0);
  const int wr = (wid >> 1) * 64, wc = (wid & 1) * 32;
  ushort* __restrict__ Out = routed ? Bg : Bs;
  const int outLd = routed ? 512 : 1024;

  int aOff[4], gOff[2], ldsA[4], ldsG[2];
#pragma unroll
  for (int i = 0; i < 4; ++i) {
    int q = (i * 4 + wid) * 64 + lane;
    int r = q >> 3, c = q & 7, lc = c ^ (r & 7);
    int arow = routed ? tokmap[row0 + r] : (row0 + r);
    aOff[i] = arow * 1024 + lc * 8;
    ldsA[i] = (i * 4 + wid) * 512;
  }
#pragma unroll
  for (int i = 0; i < 2; ++i) {
    int q = (i * 4 + wid) * 64 + lane;
    int r = q >> 3, c = q & 7, lc = c ^ (r & 7);
    gOff[i] = (colG + r) * 1024 + lc * 8;
    ldsG[i] = (i * 4 + wid) * 512;
  }

  f32x4 accG[4][2] = {};
  f32x4 accU[4][2] = {};

  auto stage = [&](ushort* A_, ushort* G_, ushort* U_, int k0) {
#pragma unroll
    for (int i = 0; i < 4; ++i) gll16(Xb + aOff[i] + k0, A_ + ldsA[i]);
#pragma unroll
    for (int i = 0; i < 2; ++i) gll16(GT + gOff[i] + k0, G_ + ldsG[i]);
#pragma unroll
    for (int i = 0; i < 2; ++i) gll16(UT + gOff[i] + k0, U_ + ldsG[i]);
  };
  auto compute = [&](const ushort* A_, const ushort* G_, const ushort* U_) {
#pragma unroll
    for (int kc = 0; kc < 2; ++kc) {
      const int clog = kc * 4 + (lane >> 4);
      s16x8 af[4], gf[2], uf[2];
#pragma unroll
      for (int fr = 0; fr < 4; ++fr) {
        int rl = wr + fr * 16 + (lane & 15);
        af[fr] = *(const s16x8*)&A_[rl * 64 + ((clog ^ (rl & 7)) << 3)];
      }
#pragma unroll
      for (int cf = 0; cf < 2; ++cf) {
        int cl = wc + cf * 16 + (lane & 15);
        int off = cl * 64 + ((clog ^ (cl & 7)) << 3);
        gf[cf] = *(const s16x8*)&G_[off];
        uf[cf] = *(const s16x8*)&U_[off];
      }
#pragma unroll
      for (int fr = 0; fr < 4; ++fr)
#pragma unroll
        for (int cf = 0; cf < 2; ++cf) {
          accG[fr][cf] = mfma_bf16(af[fr], gf[cf], accG[fr][cf]);
          accU[fr][cf] = mfma_bf16(af[fr], uf[cf], accU[fr][cf]);
        }
    }
  };

  stage(lA[0], lG[0], lU[0], 0);
  for (int k0 = 0; k0 < 1024; k0 += 128) {
    stage(lA[1], lG[1], lU[1], k0 + 64);
    asm volatile("s_waitcnt vmcnt(8)" ::: "memory");
    __builtin_amdgcn_s_barrier();
    compute(lA[0], lG[0], lU[0]);
    asm volatile("s_waitcnt lgkmcnt(0)" ::: "memory");
    __builtin_amdgcn_s_barrier();
    if (k0 + 128 < 1024) {
      stage(lA[0], lG[0], lU[0], k0 + 128);
      asm volatile("s_waitcnt vmcnt(8)" ::: "memory");
    } else {
      asm volatile("s_waitcnt vmcnt(0)" ::: "memory");
    }
    __builtin_amdgcn_s_barrier();
    compute(lA[1], lG[1], lU[1]);
    asm volatile("s_waitcnt lgkmcnt(0)" ::: "memory");
    __builtin_amdgcn_s_barrier();
  }

#pragma unroll
  for (int fr = 0; fr < 4; ++fr)
#pragma unroll
    for (int r = 0; r < 4; ++r) {
      const int row = row0 + wr + fr * 16 + ((lane >> 4) << 2) + r;
      const float sc = routed ? rowscale[row] : scales[row * 4 + 2];
#pragma unroll
      for (int cf = 0; cf < 2; ++cf) {
        const int col = col0 + wc + cf * 16 + (lane & 15);
        float g = accG[fr][cf][r];
        float u = accU[fr][cf][r];
        float a = 0.5f * g * (1.0f + erff(g * 0.70710678118654752f));
        Out[(size_t)row * outLd + col] = f2b(a * u * sc);
      }
    }
}

// ---------------- GEMM2 (2-phase pipelined): down-projection -----------------
// ROUTED: out_r[row][h] = Bg[row] @ down_e  (bf16), K=512.
// SHARED: out[t][h] = Bs[t] @ down_s + out_r[row0_t][h] + out_r[row1_t][h] (f32).
template<int ROUTED>
__global__ __launch_bounds__(256) void gemm2_k(
    const ushort* __restrict__ A, const ushort* __restrict__ DT,
    const int* __restrict__ meta, const int* __restrict__ tokrows,
    const ushort* __restrict__ Rrows, ushort* __restrict__ OutB,
    float* __restrict__ OutF)
{
  __shared__ __align__(16) ushort lA[2][128 * 64];
  __shared__ __align__(16) ushort lB[2][128 * 64];
  int e = 0;
  if (ROUTED) {
    if ((int)blockIdx.y >= meta[127]) return;
    e = meta[blockIdx.y];
  }
  const int K = ROUTED ? 512 : 1024;
  const int bBase = ROUTED ? e * 512 : 4096;
  const int tid = threadIdx.x, wid = tid >> 6, lane = tid & 63;
  const int col0 = blockIdx.x * 128, row0 = blockIdx.y * 128;
  const int wr = (wid >> 1) * 64, wc = (wid & 1) * 64;

  int aOff[4], bOff[4], lds[4];
#pragma unroll
  for (int i = 0; i < 4; ++i) {
    int q = (i * 4 + wid) * 64 + lane;
    int r = q >> 3, c = q & 7, lc = c ^ (r & 7);
    aOff[i] = (row0 + r) * K + lc * 8;
    bOff[i] = (col0 + r) * 5120 + bBase + lc * 8;
    lds[i]  = (i * 4 + wid) * 512;
  }
  f32x4 acc[4][4] = {};

  auto stage = [&](ushort* A_, ushort* B_, int k0) {
#pragma unroll
    for (int i = 0; i < 4; ++i) gll16(A + aOff[i] + k0, A_ + lds[i]);
#pragma unroll
    for (int i = 0; i < 4; ++i) gll16(DT + bOff[i] + k0, B_ + lds[i]);
  };
  auto compute = [&](const ushort* A_, const ushort* B_) {
#pragma unroll
    for (int kc = 0; kc < 2; ++kc) {
      const int clog = kc * 4 + (lane >> 4);
      s16x8 af[4], bf[4];
#pragma unroll
      for (int fr = 0; fr < 4; ++fr) {
        int rl = wr + fr * 16 + (lane & 15);
        af[fr] = *(const s16x8*)&A_[rl * 64 + ((clog ^ (rl & 7)) << 3)];
      }
#pragma unroll
      for (int cf = 0; cf < 4; ++cf) {
        int cl = wc + cf * 16 + (lane & 15);
        bf[cf] = *(const s16x8*)&B_[cl * 64 + ((clog ^ (cl & 7)) << 3)];
      }
#pragma unroll
      for (int fr = 0; fr < 4; ++fr)
#pragma unroll
        for (int cf = 0; cf < 4; ++cf)
          acc[fr][cf] = mfma_bf16(af[fr], bf[cf], acc[fr][cf]);
    }
  };

  stage(lA[0], lB[0], 0);
  for (int k0 = 0; k0 < K; k0 += 128) {
    stage(lA[1], lB[1], k0 + 64);
    asm volatile("s_waitcnt vmcnt(8)" ::: "memory");
    __builtin_amdgcn_s_barrier();
    compute(lA[0], lB[0]);
    asm volatile("s_waitcnt lgkmcnt(0)" ::: "memory");
    __builtin_amdgcn_s_barrier();
    if (k0 + 128 < K) {
      stage(lA[0], lB[0], k0 + 128);
      asm volatile("s_waitcnt vmcnt(8)" ::: "memory");
    } else {
      asm volatile("s_waitcnt vmcnt(0)" ::: "memory");
    }
    __builtin_amdgcn_s_barrier();
    compute(lA[1], lB[1]);
    asm volatile("s_waitcnt lgkmcnt(0)" ::: "memory");
    __builtin_amdgcn_s_barrier();
  }

#pragma unroll
  for (int fr = 0; fr < 4; ++fr)
#pragma unroll
    for (int r = 0; r < 4; ++r) {
      const int row = row0 + wr + fr * 16 + ((lane >> 4) << 2) + r;
      if (ROUTED) {
#pragma unroll
        for (int cf = 0; cf < 4; ++cf) {
          const int col = col0 + wc + cf * 16 + (lane & 15);
          OutB[row * 1024 + col] = f2b(acc[fr][cf][r]);
        }
      } else {
        const int r0 = tokrows[row * 2], r1 = tokrows[row * 2 + 1];
#pragma unroll
        for (int cf = 0; cf < 4; ++cf) {
          const int col = col0 + wc + cf * 16 + (lane & 15);
          float v = acc[fr][cf][r]
                  + b2f(Rrows[r0 * 1024 + col]) + b2f(Rrows[r1 * 1024 + col]);
          OutF[row * 1024 + col] = v;
        }
      }
    }
}

extern "C" void kernel_launch(void* const* d_in, const int* in_sizes, int n_in,
                              void* d_out, int out_size, void* d_ws, size_t ws_size,
                              hipStream_t stream) {
  const float* X    = (const float*)d_in[0];   // [4096,1024]
  const int*   task = (const int*)  d_in[1];
  const float* Gw   = (const float*)d_in[2];   // [8,1024]
  const float* Temb = (const float*)d_in[3];   // [3,1024]
  const float* Weg  = (const float*)d_in[4];   // [8,1024,512]
  const float* Weu  = (const float*)d_in[5];   // [8,1024,512]
  const float* Wed  = (const float*)d_in[6];   // [8,512,1024]
  const float* Wsg  = (const float*)d_in[7];   // [1024,1024]
  const float* Wsu  = (const float*)d_in[8];   // [1024,1024]
  const float* Wsd  = (const float*)d_in[9];   // [1024,1024]
  const float* Wc   = (const float*)d_in[10];  // [1024,2]

  char* ws = (char*)d_ws;
  float*  scales   = (float*)(ws + 0x00000);        // 4096*4 f32
  int*    topk     = (int*)  (ws + 0x10000);        // 4096*2
  int*    tokmap   = (int*)  (ws + 0x18000);        // 9216
  int*    tokrows  = (int*)  (ws + 0x22000);        // 4096*2
  float*  rowscale = (float*)(ws + 0x2A000);        // 9216
  int*    meta     = (int*)  (ws + 0x34000);        // 128
  ushort* Xb       = (ushort*)(ws + 0x40000);       // 4096*1024
  ushort* GT       = Xb + 4096 * 1024;              // 5120*1024
  ushort* UT       = GT + 5120 * 1024;
  ushort* DT       = UT + 5120 * 1024;              // 1024*5120
  ushort* Bg       = DT + 1024 * 5120;              // 9216*512
  ushort* Bs       = Bg + 9216 * 512;               // 4096*1024
  ushort* out_r    = Bs + 4096 * 1024;              // 9216*1024

  transpose_k<0><<<dim3(16, 32, 16), 256, 0, stream>>>(Weg, Weu, nullptr, GT, UT, nullptr);
  transpose_k<1><<<dim3(32, 16, 8), 256, 0, stream>>>(Wed, nullptr, nullptr, DT, nullptr, nullptr);
  transpose_k<2><<<dim3(32, 32, 3), 256, 0, stream>>>(
      Wsg, Wsu, Wsd, GT + 4096 * 1024, UT + 4096 * 1024, DT + 4096);

  router_k<<<1024, 256, 0, stream>>>(X, Gw, Temb, task, Wc, scales, topk, Xb);
  indexbuild_k<<<1, 256, 0, stream>>>(topk, scales, tokmap, tokrows, rowscale, meta);

  gemm1_k<<<dim3(16, 104), 256, 0, stream>>>(Xb, GT, UT, scales, tokmap, rowscale, meta, Bg, Bs);

  gemm2_k<1><<<dim3(8, 72), 256, 0, stream>>>(Bg, DT, meta, tokrows, (const ushort*)nullptr, out_r, (float*)nullptr);
  gemm2_k<0><<<dim3(8, 32), 256, 0, stream>>>(Bs, DT, meta, tokrows, out_r, (ushort*)nullptr, (float*)d_out);
}

// Round 6
// 155.727 us; speedup vs baseline: 1.1680x; 1.1680x over previous
//
#include <hip/hip_runtime.h>
#include <hip/hip_bf16.h>

// DeepseekMoE fused, top-2 SPARSE routed experts, 64x64-tile GEMMs for TLP:
//   router (f32, + bf16 cast of X) -> index build (per-expert token buckets,
//   64-aligned segments) -> MERGED gathered+shared gate/up GEMM
//   (+gelu*u*scale) -> routed down GEMM (bf16 rows) -> shared down GEMM with
//   fused combine. Device tensors are FLOAT32; GEMMs bf16, f32 accumulate.
// 64x64 tiles / 4 waves (2x2 of 32x32) / 24KB (g1) / 16KB (g2) LDS ->
// ~5-6 resident blocks/CU: latency hidden by TLP, not intra-block pipelining
// (r5 showed dbuf+vmcnt pipeline loses more occupancy than it hides).
// T=4096, H=1024, E=8, I=512, IS=1024.

typedef short  s16x8 __attribute__((ext_vector_type(8)));
typedef __bf16 bf16x8 __attribute__((ext_vector_type(8)));
typedef float  f32x4 __attribute__((ext_vector_type(4)));

__device__ __forceinline__ float b2f(ushort u) {
  union { unsigned int i; float f; } v; v.i = ((unsigned int)u) << 16; return v.f;
}
__device__ __forceinline__ ushort f2b(float f) {
  union { float f; unsigned int i; } v; v.f = f;
  unsigned int r = v.i + 0x7fffu + ((v.i >> 16) & 1u);
  return (ushort)(r >> 16);
}
__device__ __forceinline__ f32x4 mfma_bf16(s16x8 a, s16x8 b, f32x4 c) {
  return __builtin_amdgcn_mfma_f32_16x16x32_bf16(
      __builtin_bit_cast(bf16x8, a), __builtin_bit_cast(bf16x8, b), c, 0, 0, 0);
}
__device__ __forceinline__ void gll16(const ushort* g, const ushort* l) {
  __builtin_amdgcn_global_load_lds(
      (const __attribute__((address_space(1))) unsigned int*)g,
      (__attribute__((address_space(3))) unsigned int*)l, 16, 0, 0);
}

// -------- tiled transpose + cast, 3 tight-grid variants ----------------------
template<int MODE>
__global__ __launch_bounds__(256) void transpose_k(
    const float* __restrict__ S0, const float* __restrict__ S1,
    const float* __restrict__ S2, ushort* __restrict__ D0,
    ushort* __restrict__ D1, ushort* __restrict__ D2)
{
  const int z = blockIdx.z;
  const float* src; ushort* dst; int srcLd, dstLd;
  if (MODE == 0) {
    src = (z < 8 ? S0 + (size_t)z * 512 * 1024 : S1 + (size_t)(z - 8) * 512 * 1024);
    dst = (z < 8 ? D0 + (size_t)z * 512 * 1024 : D1 + (size_t)(z - 8) * 512 * 1024);
    srcLd = 512; dstLd = 1024;
  } else if (MODE == 1) {
    src = S0 + (size_t)z * 512 * 1024; dst = D0 + (size_t)z * 512;
    srcLd = 1024; dstLd = 5120;
  } else {
    src = (z == 0 ? S0 : z == 1 ? S1 : S2);
    dst = (z == 0 ? D0 : z == 1 ? D1 : D2);
    srcLd = 1024; dstLd = (z == 2 ? 5120 : 1024);
  }
  __shared__ float tile[32][33];
  const int c0 = blockIdx.x * 32, r0 = blockIdx.y * 32;
  const int tx = threadIdx.x & 31, ty = threadIdx.x >> 5;
#pragma unroll
  for (int j = 0; j < 4; ++j)
    tile[ty + j * 8][tx] = src[(size_t)(r0 + ty + j * 8) * srcLd + c0 + tx];
  __syncthreads();
#pragma unroll
  for (int j = 0; j < 4; ++j)
    dst[(size_t)(c0 + ty + j * 8) * dstLd + r0 + tx] = f2b(tile[tx][ty + j * 8]);
}

// ---------------- router (f32) + X->bf16 cast --------------------------------
__global__ __launch_bounds__(256) void router_k(
    const float* __restrict__ X, const float* __restrict__ Gw,
    const float* __restrict__ Temb, const int* __restrict__ task_id,
    const float* __restrict__ Wc, float* __restrict__ scales,
    int* __restrict__ topk, ushort* __restrict__ Xb)
{
  const int wid = threadIdx.x >> 6, lane = threadIdx.x & 63;
  const int t = blockIdx.x * 4 + wid;
  const float* xr = X + t * 1024;
  const float* er = Temb + task_id[0] * 1024;

  float x[16], xe[16];
#pragma unroll
  for (int c = 0; c < 4; ++c) {
    float4 v = *(const float4*)&xr[c * 256 + lane * 4];
    float4 e = *(const float4*)&er[c * 256 + lane * 4];
    x[c * 4 + 0] = v.x; x[c * 4 + 1] = v.y; x[c * 4 + 2] = v.z; x[c * 4 + 3] = v.w;
    xe[c * 4 + 0] = v.x + e.x; xe[c * 4 + 1] = v.y + e.y;
    xe[c * 4 + 2] = v.z + e.z; xe[c * 4 + 3] = v.w + e.w;
  }
#pragma unroll
  for (int c = 0; c < 4; ++c) {
    ushort4 o;
    o.x = f2b(x[c * 4 + 0]); o.y = f2b(x[c * 4 + 1]);
    o.z = f2b(x[c * 4 + 2]); o.w = f2b(x[c * 4 + 3]);
    *(ushort4*)&Xb[t * 1024 + c * 256 + lane * 4] = o;
  }
  float logit[8];
#pragma unroll
  for (int e = 0; e < 8; ++e) {
    float p = 0.f;
#pragma unroll
    for (int c = 0; c < 4; ++c) {
      float4 g = *(const float4*)&Gw[e * 1024 + c * 256 + lane * 4];
      p += xe[c * 4] * g.x + xe[c * 4 + 1] * g.y + xe[c * 4 + 2] * g.z + xe[c * 4 + 3] * g.w;
    }
#pragma unroll
    for (int off = 32; off; off >>= 1) p += __shfl_xor(p, off);
    logit[e] = p;
  }
  float m = logit[0];
#pragma unroll
  for (int e = 1; e < 8; ++e) m = fmaxf(m, logit[e]);
  float pr[8], s = 0.f;
#pragma unroll
  for (int e = 0; e < 8; ++e) { pr[e] = expf(logit[e] - m); s += pr[e]; }
  float inv = 1.f / s;
#pragma unroll
  for (int e = 0; e < 8; ++e) pr[e] *= inv;
  int i1 = 0; float m1 = pr[0];
#pragma unroll
  for (int e = 1; e < 8; ++e) if (pr[e] > m1) { m1 = pr[e]; i1 = e; }
  int i2 = -1; float m2 = -1.f;
#pragma unroll
  for (int e = 0; e < 8; ++e) if (e != i1 && pr[e] > m2) { m2 = pr[e]; i2 = e; }
  float dn = 1.f / (m1 + m2 + 1e-20f);
  float w1 = m1 * dn, w2 = m2 * dn;

  float a0 = 0.f, a1 = 0.f;
#pragma unroll
  for (int c = 0; c < 4; ++c)
#pragma unroll
    for (int j = 0; j < 4; ++j) {
      int h = c * 256 + lane * 4 + j;
      a0 += x[c * 4 + j] * Wc[h * 2];
      a1 += x[c * 4 + j] * Wc[h * 2 + 1];
    }
#pragma unroll
  for (int off = 32; off; off >>= 1) {
    a0 += __shfl_xor(a0, off); a1 += __shfl_xor(a1, off);
  }
  float am = fmaxf(a0, a1);
  float ea0 = expf(a0 - am), ea1 = expf(a1 - am);
  float al0 = ea0 / (ea0 + ea1), al1 = ea1 / (ea0 + ea1);

  if (lane == 0) {
    scales[t * 4 + 0] = al0 * w1;
    scales[t * 4 + 1] = al0 * w2;
    scales[t * 4 + 2] = al1;
    topk[t * 2 + 0] = i1;
    topk[t * 2 + 1] = i2;
  }
}

// ---------------- index build: per-expert 64-aligned token buckets -----------
// meta[0..134] = row-block -> expert; meta[255] = total 64-row blocks.
__global__ __launch_bounds__(256) void indexbuild_k(
    const int* __restrict__ topk, const float* __restrict__ scales,
    int* __restrict__ tokmap, int* __restrict__ tokrows,
    float* __restrict__ rowscale, int* __restrict__ meta)
{
  __shared__ int cnt[8], cnt2[8], base[8];
  const int tid = threadIdx.x;
  if (tid < 8) { cnt[tid] = 0; cnt2[tid] = 0; }
  __syncthreads();
  for (int t = tid; t < 4096; t += 256) {
    atomicAdd(&cnt[topk[t * 2]], 1);
    atomicAdd(&cnt[topk[t * 2 + 1]], 1);
  }
  __syncthreads();
  if (tid == 0) {
    int nb = 0;
    for (int e = 0; e < 8; ++e) {
      base[e] = nb * 64;
      int blocks = (cnt[e] + 63) >> 6;
      for (int j = 0; j < blocks; ++j) meta[nb + j] = e;
      nb += blocks;
    }
    meta[255] = nb;
  }
  __syncthreads();
  for (int t = tid; t < 4096; t += 256) {
#pragma unroll
    for (int r = 0; r < 2; ++r) {
      int e = topk[t * 2 + r];
      int slot = atomicAdd(&cnt2[e], 1);
      int row = base[e] + slot;
      tokmap[row] = t;
      rowscale[row] = scales[t * 4 + r];
      tokrows[t * 2 + r] = row;
    }
  }
  __syncthreads();
  for (int e = 0; e < 8; ++e) {
    int c = cnt[e], R = ((c + 63) >> 6) << 6;
    for (int j = c + tid; j < R; j += 256) {
      tokmap[base[e] + j] = 0;
      rowscale[base[e] + j] = 0.f;
    }
  }
}

// ------- MERGED GEMM1: routed + shared gate/up, 64x64 tiles ------------------
// grid (16, 200). y<136: routed 64-row expert block (x<8, y<meta[255]),
//                 y>=136: shared token block (all 16 x).
// 4 waves (2x2), wave = 32x32, dual G/U acc. LDS 24KB, single-buffered.
__global__ __launch_bounds__(256) void gemm1_k(
    const ushort* __restrict__ Xb, const ushort* __restrict__ GT,
    const ushort* __restrict__ UT, const float* __restrict__ scales,
    const int* __restrict__ tokmap, const float* __restrict__ rowscale,
    const int* __restrict__ meta, ushort* __restrict__ Bg,
    ushort* __restrict__ Bs)
{
  __shared__ __align__(16) ushort lA[64 * 64];
  __shared__ __align__(16) ushort lG[64 * 64];
  __shared__ __align__(16) ushort lU[64 * 64];
  const int x = blockIdx.x, y = blockIdx.y;
  const bool routed = y < 136;
  if (routed && (x >= 8 || y >= meta[255])) return;

  const int tid = threadIdx.x, wid = tid >> 6, lane = tid & 63;
  const int col0 = x * 64;
  const int row0 = routed ? y * 64 : (y - 136) * 64;
  const int colG = routed ? (meta[y] * 512 + col0) : (4096 + col0);
  const int wr = (wid >> 1) * 32, wc = (wid & 1) * 32;
  ushort* __restrict__ Out = routed ? Bg : Bs;
  const int outLd = routed ? 512 : 1024;

  // staging: physical 16B chunk (r,c) holds logical chunk c^(r&7) (swizzle on
  // the GLOBAL source address; LDS destination stays linear per gll_lds rules)
  int aOff[2], gOff[2], ldsO[2];
#pragma unroll
  for (int i = 0; i < 2; ++i) {
    int q = i * 256 + tid;               // 512 chunks of 16B = 64x64 bf16 tile
    int r = q >> 3, c = q & 7, lc = c ^ (r & 7);
    int arow = routed ? tokmap[row0 + r] : (row0 + r);
    aOff[i] = arow * 1024 + lc * 8;
    gOff[i] = (colG + r) * 1024 + lc * 8;
    ldsO[i] = q * 8 - lane * 8 - (lane * 8 - lane * 8); // wave-uniform base + lane*8
    ldsO[i] = (i * 256 + (tid & ~63)) * 8;
  }

  f32x4 accG[2][2] = {};
  f32x4 accU[2][2] = {};
  for (int k0 = 0; k0 < 1024; k0 += 64) {
    if (k0) __syncthreads();
#pragma unroll
    for (int i = 0; i < 2; ++i) gll16(Xb + aOff[i] + k0, lA + ldsO[i] + lane * 8);
#pragma unroll
    for (int i = 0; i < 2; ++i) gll16(GT + gOff[i] + k0, lG + ldsO[i] + lane * 8);
#pragma unroll
    for (int i = 0; i < 2; ++i) gll16(UT + gOff[i] + k0, lU + ldsO[i] + lane * 8);
    __syncthreads();
#pragma unroll
    for (int kc = 0; kc < 2; ++kc) {
      const int clog = kc * 4 + (lane >> 4);
      s16x8 af[2], gf[2], uf[2];
#pragma unroll
      for (int fr = 0; fr < 2; ++fr) {
        int rl = wr + fr * 16 + (lane & 15);
        af[fr] = *(const s16x8*)&lA[rl * 64 + ((clog ^ (rl & 7)) << 3)];
      }
#pragma unroll
      for (int cf = 0; cf < 2; ++cf) {
        int cl = wc + cf * 16 + (lane & 15);
        int off = cl * 64 + ((clog ^ (cl & 7)) << 3);
        gf[cf] = *(const s16x8*)&lG[off];
        uf[cf] = *(const s16x8*)&lU[off];
      }
#pragma unroll
      for (int fr = 0; fr < 2; ++fr)
#pragma unroll
        for (int cf = 0; cf < 2; ++cf) {
          accG[fr][cf] = mfma_bf16(af[fr], gf[cf], accG[fr][cf]);
          accU[fr][cf] = mfma_bf16(af[fr], uf[cf], accU[fr][cf]);
        }
    }
  }
#pragma unroll
  for (int fr = 0; fr < 2; ++fr)
#pragma unroll
    for (int r = 0; r < 4; ++r) {
      const int row = row0 + wr + fr * 16 + ((lane >> 4) << 2) + r;
      const float sc = routed ? rowscale[row] : scales[row * 4 + 2];
#pragma unroll
      for (int cf = 0; cf < 2; ++cf) {
        const int col = col0 + wc + cf * 16 + (lane & 15);
        float g = accG[fr][cf][r];
        float u = accU[fr][cf][r];
        float a = 0.5f * g * (1.0f + erff(g * 0.70710678118654752f));
        Out[(size_t)row * outLd + col] = f2b(a * u * sc);
      }
    }
}

// ---------------- GEMM2: down-projection, 64x64 tiles ------------------------
// ROUTED: out_r[row][h] = Bg[row] @ down_e  (bf16), K=512.  grid (16, 136)
// SHARED: out[t][h] = Bs[t] @ down_s + out_r[r0][h] + out_r[r1][h] (f32). (16,64)
template<int ROUTED>
__global__ __launch_bounds__(256) void gemm2_k(
    const ushort* __restrict__ A, const ushort* __restrict__ DT,
    const int* __restrict__ meta, const int* __restrict__ tokrows,
    const ushort* __restrict__ Rrows, ushort* __restrict__ OutB,
    float* __restrict__ OutF)
{
  __shared__ __align__(16) ushort lA[64 * 64];
  __shared__ __align__(16) ushort lB[64 * 64];
  int e = 0;
  if (ROUTED) {
    if ((int)blockIdx.y >= meta[255]) return;
    e = meta[blockIdx.y];
  }
  const int K = ROUTED ? 512 : 1024;
  const int bBase = ROUTED ? e * 512 : 4096;
  const int tid = threadIdx.x, wid = tid >> 6, lane = tid & 63;
  const int col0 = blockIdx.x * 64, row0 = blockIdx.y * 64;
  const int wr = (wid >> 1) * 32, wc = (wid & 1) * 32;

  int aOff[2], bOff[2], ldsO[2];
#pragma unroll
  for (int i = 0; i < 2; ++i) {
    int q = i * 256 + tid;
    int r = q >> 3, c = q & 7, lc = c ^ (r & 7);
    aOff[i] = (row0 + r) * K + lc * 8;
    bOff[i] = (col0 + r) * 5120 + bBase + lc * 8;
    ldsO[i] = (i * 256 + (tid & ~63)) * 8;
  }
  f32x4 acc[2][2] = {};
  for (int k0 = 0; k0 < K; k0 += 64) {
    if (k0) __syncthreads();
#pragma unroll
    for (int i = 0; i < 2; ++i) gll16(A + aOff[i] + k0, lA + ldsO[i] + lane * 8);
#pragma unroll
    for (int i = 0; i < 2; ++i) gll16(DT + bOff[i] + k0, lB + ldsO[i] + lane * 8);
    __syncthreads();
#pragma unroll
    for (int kc = 0; kc < 2; ++kc) {
      const int clog = kc * 4 + (lane >> 4);
      s16x8 af[2], bf[2];
#pragma unroll
      for (int fr = 0; fr < 2; ++fr) {
        int rl = wr + fr * 16 + (lane & 15);
        af[fr] = *(const s16x8*)&lA[rl * 64 + ((clog ^ (rl & 7)) << 3)];
      }
#pragma unroll
      for (int cf = 0; cf < 2; ++cf) {
        int cl = wc + cf * 16 + (lane & 15);
        bf[cf] = *(const s16x8*)&lB[cl * 64 + ((clog ^ (cl & 7)) << 3)];
      }
#pragma unroll
      for (int fr = 0; fr < 2; ++fr)
#pragma unroll
        for (int cf = 0; cf < 2; ++cf)
          acc[fr][cf] = mfma_bf16(af[fr], bf[cf], acc[fr][cf]);
    }
  }
#pragma unroll
  for (int fr = 0; fr < 2; ++fr)
#pragma unroll
    for (int r = 0; r < 4; ++r) {
      const int row = row0 + wr + fr * 16 + ((lane >> 4) << 2) + r;
      if (ROUTED) {
#pragma unroll
        for (int cf = 0; cf < 2; ++cf) {
          const int col = col0 + wc + cf * 16 + (lane & 15);
          OutB[row * 1024 + col] = f2b(acc[fr][cf][r]);
        }
      } else {
        const int r0 = tokrows[row * 2], r1 = tokrows[row * 2 + 1];
#pragma unroll
        for (int cf = 0; cf < 2; ++cf) {
          const int col = col0 + wc + cf * 16 + (lane & 15);
          float v = acc[fr][cf][r]
                  + b2f(Rrows[r0 * 1024 + col]) + b2f(Rrows[r1 * 1024 + col]);
          OutF[row * 1024 + col] = v;
        }
      }
    }
}

extern "C" void kernel_launch(void* const* d_in, const int* in_sizes, int n_in,
                              void* d_out, int out_size, void* d_ws, size_t ws_size,
                              hipStream_t stream) {
  const float* X    = (const float*)d_in[0];   // [4096,1024]
  const int*   task = (const int*)  d_in[1];
  const float* Gw   = (const float*)d_in[2];   // [8,1024]
  const float* Temb = (const float*)d_in[3];   // [3,1024]
  const float* Weg  = (const float*)d_in[4];   // [8,1024,512]
  const float* Weu  = (const float*)d_in[5];   // [8,1024,512]
  const float* Wed  = (const float*)d_in[6];   // [8,512,1024]
  const float* Wsg  = (const float*)d_in[7];   // [1024,1024]
  const float* Wsu  = (const float*)d_in[8];   // [1024,1024]
  const float* Wsd  = (const float*)d_in[9];   // [1024,1024]
  const float* Wc   = (const float*)d_in[10];  // [1024,2]

  char* ws = (char*)d_ws;
  float*  scales   = (float*)(ws + 0x00000);        // 4096*4 f32
  int*    topk     = (int*)  (ws + 0x10000);        // 4096*2
  int*    tokmap   = (int*)  (ws + 0x18000);        // <=8640
  int*    tokrows  = (int*)  (ws + 0x22000);        // 4096*2
  float*  rowscale = (float*)(ws + 0x2A000);        // <=8640
  int*    meta     = (int*)  (ws + 0x34000);        // 256
  ushort* Xb       = (ushort*)(ws + 0x40000);       // 4096*1024
  ushort* GT       = Xb + 4096 * 1024;              // 5120*1024
  ushort* UT       = GT + 5120 * 1024;
  ushort* DT       = UT + 5120 * 1024;              // 1024*5120
  ushort* Bg       = DT + 1024 * 5120;              // 9216*512
  ushort* Bs       = Bg + 9216 * 512;               // 4096*1024
  ushort* out_r    = Bs + 4096 * 1024;              // 9216*1024

  transpose_k<0><<<dim3(16, 32, 16), 256, 0, stream>>>(Weg, Weu, nullptr, GT, UT, nullptr);
  transpose_k<1><<<dim3(32, 16, 8), 256, 0, stream>>>(Wed, nullptr, nullptr, DT, nullptr, nullptr);
  transpose_k<2><<<dim3(32, 32, 3), 256, 0, stream>>>(
      Wsg, Wsu, Wsd, GT + 4096 * 1024, UT + 4096 * 1024, DT + 4096);

  router_k<<<1024, 256, 0, stream>>>(X, Gw, Temb, task, Wc, scales, topk, Xb);
  indexbuild_k<<<1, 256, 0, stream>>>(topk, scales, tokmap, tokrows, rowscale, meta);

  gemm1_k<<<dim3(16, 200), 256, 0, stream>>>(Xb, GT, UT, scales, tokmap, rowscale, meta, Bg, Bs);

  gemm2_k<1><<<dim3(16, 136), 256, 0, stream>>>(Bg, DT, meta, tokrows, (const ushort*)nullptr, out_r, (float*)nullptr);
  gemm2_k<0><<<dim3(16, 64), 256, 0, stream>>>(Bs, DT, meta, tokrows, out_r, (ushort*)nullptr, (float*)d_out);
}